// Round 1
// baseline (2026.003 us; speedup 1.0000x reference)
//
#include <hip/hip_runtime.h>
#include <hip/hip_bf16.h>

#define N_NODES 50000
#define N_EDGES 800000
#define N_REL   3
#define F_IN    256
#define CH      128
#define BATCH   4096
#define DT      0.25f

// ---------------------------------------------------------------------------
// Detect whether integer inputs are int64 (reference astype) or int32 (JAX
// default without x64). If int64, odd int32 words are all-zero high words.
// ---------------------------------------------------------------------------
__global__ void k_detect(const int* __restrict__ ei, int* __restrict__ flag) {
  int lane = threadIdx.x;           // 64 threads
  int v = ei[2 * lane + 1];         // int32 positions 1,3,...,127 (< 2E both ways)
  unsigned long long m = __ballot(v != 0);
  if (lane == 0) flag[0] = (m == 0ull) ? 1 : 0;  // 1 => int64
}

// in-degree histogram over col
__global__ void k_hist(const int* __restrict__ ei, long eoff,
                       const int* __restrict__ flag, int* __restrict__ deg) {
  int e = blockIdx.x * blockDim.x + threadIdx.x;
  if (e >= N_EDGES) return;
  int i64 = flag[0];
  long idx = eoff + e;
  int d = i64 ? ei[2 * idx] : ei[idx];   // little-endian low word
  atomicAdd(&deg[d], 1);
}

__global__ void k_dinv(const int* __restrict__ deg, float* __restrict__ dinv) {
  int i = blockIdx.x * blockDim.x + threadIdx.x;
  if (i >= N_NODES) return;
  int d = deg[i];
  dinv[i] = d > 0 ? rsqrtf((float)d) : 0.0f;
}

// single-block exclusive prefix scan of deg -> off[0..N]
__global__ void k_scan(const int* __restrict__ deg, int* __restrict__ off) {
  __shared__ int sm[1024];
  int tid = threadIdx.x;
  const int PER = (N_NODES + 1023) / 1024;   // 49
  int base = tid * PER;
  int s = 0;
  for (int i = 0; i < PER; ++i) { int idx = base + i; if (idx < N_NODES) s += deg[idx]; }
  sm[tid] = s;
  __syncthreads();
  for (int d = 1; d < 1024; d <<= 1) {
    int v = 0;
    if (tid >= d) v = sm[tid - d];
    __syncthreads();
    sm[tid] += v;
    __syncthreads();
  }
  int run = sm[tid] - s;  // exclusive prefix
  for (int i = 0; i < PER; ++i) {
    int idx = base + i;
    if (idx < N_NODES) { off[idx] = run; run += deg[idx]; }
  }
  if (tid == 1023) off[N_NODES] = run;   // == E
}

// scatter edges into CSR-by-destination slots; weight = dinv[src]*dinv[dst]
__global__ void k_fill(const int* __restrict__ ei, long roff, long coff,
                       const int* __restrict__ flag, const int* __restrict__ off,
                       int* __restrict__ cur, const float* __restrict__ dinv,
                       int* __restrict__ csr_src, float* __restrict__ csr_w) {
  int e = blockIdx.x * blockDim.x + threadIdx.x;
  if (e >= N_EDGES) return;
  int i64 = flag[0];
  long ri = roff + e, ci = coff + e;
  int s = i64 ? ei[2 * ri] : ei[ri];
  int d = i64 ? ei[2 * ci] : ei[ci];
  int pos = atomicAdd(&cur[d], 1);
  int slot = off[d] + pos;
  csr_src[slot] = s;
  csr_w[slot] = dinv[s] * dinv[d];
}

// ---------------------------------------------------------------------------
// Fused phi GEMM: P0 = X*W0^T + b0, P1 = X*W1^T + b1.
// BM=64 rows, BN=256 cols (128 phi0 | 128 phi1), KC=32, 8x8 per thread.
// fp32 vector ALU (no fp32 MFMA on CDNA4).
// ---------------------------------------------------------------------------
__global__ __launch_bounds__(256) void k_phi(
    const float* __restrict__ X,
    const float* __restrict__ W0, const float* __restrict__ b0,
    const float* __restrict__ W1, const float* __restrict__ b1,
    float* __restrict__ P0, float* __restrict__ P1) {
  __shared__ float As[32][64];    // [k][m]
  __shared__ float Bs[32][256];   // [k][n]
  int tid = threadIdx.x;
  int m0 = blockIdx.x * 64;
  int tc = tid & 31, tr = tid >> 5;      // tc 0..31 (n), tr 0..7 (m)
  int ml = tid & 63, j0 = tid >> 6;      // A-load mapping
  int nB = tid;                          // B-load row (0..255)
  const float* Wrow = (nB < 128) ? (W0 + (size_t)nB * F_IN)
                                 : (W1 + (size_t)(nB - 128) * F_IN);
  float acc[8][8] = {};
  for (int k0 = 0; k0 < F_IN; k0 += 32) {
#pragma unroll
    for (int t = 0; t < 2; ++t) {
      int j = j0 + 4 * t;                // 0..7 float4 along k
      int m = m0 + ml;
      float4 v = make_float4(0.f, 0.f, 0.f, 0.f);
      if (m < N_NODES) v = *(const float4*)(X + (size_t)m * F_IN + k0 + 4 * j);
      As[4 * j + 0][ml] = v.x; As[4 * j + 1][ml] = v.y;
      As[4 * j + 2][ml] = v.z; As[4 * j + 3][ml] = v.w;
    }
#pragma unroll
    for (int j = 0; j < 8; ++j) {
      float4 v = *(const float4*)(Wrow + k0 + 4 * j);
      Bs[4 * j + 0][nB] = v.x; Bs[4 * j + 1][nB] = v.y;
      Bs[4 * j + 2][nB] = v.z; Bs[4 * j + 3][nB] = v.w;
    }
    __syncthreads();
#pragma unroll
    for (int k = 0; k < 32; ++k) {
      float a[8], b[8];
      *(float4*)&a[0] = *(const float4*)&As[k][tr * 8];
      *(float4*)&a[4] = *(const float4*)&As[k][tr * 8 + 4];
      *(float4*)&b[0] = *(const float4*)&Bs[k][tc * 8];
      *(float4*)&b[4] = *(const float4*)&Bs[k][tc * 8 + 4];
#pragma unroll
      for (int i = 0; i < 8; ++i)
#pragma unroll
        for (int j = 0; j < 8; ++j) acc[i][j] = fmaf(a[i], b[j], acc[i][j]);
    }
    __syncthreads();
  }
  // epilogue: cols 0..127 -> P0, 128..255 -> P1, + bias
  const float* bp = (tc < 16) ? b0 : b1;
  float* P = (tc < 16) ? P0 : P1;
  int cb = (tc & 15) * 8;
  float bias[8];
#pragma unroll
  for (int j = 0; j < 8; ++j) bias[j] = bp[cb + j];
#pragma unroll
  for (int i = 0; i < 8; ++i) {
    int m = m0 + tr * 8 + i;
    if (m < N_NODES) {
      float4 o0 = make_float4(acc[i][0] + bias[0], acc[i][1] + bias[1],
                              acc[i][2] + bias[2], acc[i][3] + bias[3]);
      float4 o1 = make_float4(acc[i][4] + bias[4], acc[i][5] + bias[5],
                              acc[i][6] + bias[6], acc[i][7] + bias[7]);
      *(float4*)(P + (size_t)m * CH + cb) = o0;
      *(float4*)(P + (size_t)m * CH + cb + 4) = o1;
    }
  }
}

// ---------------------------------------------------------------------------
// out[i] = wscale * sum_e csr_w[e]*xc[src[e]]  +  aself*xc[i]  +  beta*other[i]
// One wave per destination node; lane holds 2 channels (float2 of C=128).
// other/out may alias elementwise (read-before-write by same thread).
// ---------------------------------------------------------------------------
__global__ __launch_bounds__(256) void k_prop(
    const float* __restrict__ xc, const float* __restrict__ other,
    float* __restrict__ out,
    const int* __restrict__ off, const int* __restrict__ csr_src,
    const float* __restrict__ csr_w,
    float wscale, float aself, float beta) {
  int node = blockIdx.x * 4 + (threadIdx.x >> 6);
  if (node >= N_NODES) return;
  int lane = threadIdx.x & 63;
  const float2* x2 = (const float2*)xc;
  float2 acc = make_float2(0.f, 0.f);
  int e0 = off[node], e1 = off[node + 1];
  for (int e = e0; e < e1; ++e) {
    int s = csr_src[e];
    float w = csr_w[e] * wscale;
    float2 v = x2[(size_t)s * 64 + lane];
    acc.x = fmaf(w, v.x, acc.x);
    acc.y = fmaf(w, v.y, acc.y);
  }
  float2 sv = x2[(size_t)node * 64 + lane];
  float2 ov = ((const float2*)other)[(size_t)node * 64 + lane];
  float2 o;
  o.x = acc.x + aself * sv.x + beta * ov.x;
  o.y = acc.y + aself * sv.y + beta * ov.y;
  ((float2*)out)[(size_t)node * 64 + lane] = o;
}

__global__ void k_gather(const float* __restrict__ x, const int* __restrict__ batch,
                         const int* __restrict__ flag, float* __restrict__ out, int r) {
  int idx = blockIdx.x * blockDim.x + threadIdx.x;
  int b = idx >> 6, lane = idx & 63;
  if (b >= BATCH) return;
  int i64 = flag[0];
  int node = i64 ? batch[2 * b] : batch[b];
  ((float2*)out)[(size_t)b * (N_REL * 64) + r * 64 + lane] =
      ((const float2*)x)[(size_t)node * 64 + lane];
}

extern "C" void kernel_launch(void* const* d_in, const int* in_sizes, int n_in,
                              void* d_out, int out_size, void* d_ws, size_t ws_size,
                              hipStream_t stream) {
  const float* features   = (const float*)d_in[0];
  const int*   edge_index = (const int*)d_in[1];
  const int*   batch_nodes= (const int*)d_in[2];
  const float* lin0_w     = (const float*)d_in[3];
  const float* lin0_b     = (const float*)d_in[4];
  const float* lin1_w     = (const float*)d_in[5];
  const float* lin1_b     = (const float*)d_in[6];
  float* out = (float*)d_out;

  char* w = (char*)d_ws;
  size_t o = 0;
  auto nxt = [&](size_t bytes) {
    char* p = w + o;
    o = (o + bytes + 255) & ~(size_t)255;
    return p;
  };
  int*   flag    = (int*)  nxt(256);
  int*   deg     = (int*)  nxt((size_t)N_NODES * 4);
  int*   cur     = (int*)  nxt((size_t)N_NODES * 4);
  float* dinv    = (float*)nxt((size_t)N_NODES * 4);
  int*   off     = (int*)  nxt((size_t)(N_NODES + 1) * 4);
  int*   csr_src = (int*)  nxt((size_t)N_EDGES * 4);
  float* csr_w   = (float*)nxt((size_t)N_EDGES * 4);
  float* P0      = (float*)nxt((size_t)N_NODES * CH * 4);
  float* P1      = (float*)nxt((size_t)N_NODES * CH * 4);
  float* Ab      = (float*)nxt((size_t)N_NODES * CH * 4);

  k_detect<<<1, 64, 0, stream>>>(edge_index, flag);

  const float h2 = DT * DT;
  for (int r = 0; r < N_REL; ++r) {
    long roff = (long)r * 2 * N_EDGES;
    long coff = roff + N_EDGES;
    hipMemsetAsync(deg, 0, (size_t)N_NODES * 4, stream);
    hipMemsetAsync(cur, 0, (size_t)N_NODES * 4, stream);
    k_hist<<<(N_EDGES + 255) / 256, 256, 0, stream>>>(edge_index, coff, flag, deg);
    k_dinv<<<(N_NODES + 255) / 256, 256, 0, stream>>>(deg, dinv);
    k_scan<<<1, 1024, 0, stream>>>(deg, off);
    k_fill<<<(N_EDGES + 255) / 256, 256, 0, stream>>>(edge_index, roff, coff, flag,
                                                      off, cur, dinv, csr_src, csr_w);
    k_phi<<<(N_NODES + 63) / 64, 256, 0, stream>>>(
        features, lin0_w + (size_t)r * CH * F_IN, lin0_b + (size_t)r * CH,
        lin1_w + (size_t)r * CH * F_IN, lin1_b + (size_t)r * CH, P0, P1);
    // init: x1 = dt*phi1 + (dt^2/2)*A_hat*phi0 + phi0         -> Ab
    k_prop<<<(N_NODES + 3) / 4, 256, 0, stream>>>(P0, P1, Ab, off, csr_src, csr_w,
                                                  0.5f * h2, 1.0f, DT);
    // steps: xn = dt^2*A_hat*xc + 2*xc - xp   (3 steps, 2-buffer rotation)
    k_prop<<<(N_NODES + 3) / 4, 256, 0, stream>>>(Ab, P0, P0, off, csr_src, csr_w,
                                                  h2, 2.0f, -1.0f);
    k_prop<<<(N_NODES + 3) / 4, 256, 0, stream>>>(P0, Ab, Ab, off, csr_src, csr_w,
                                                  h2, 2.0f, -1.0f);
    k_prop<<<(N_NODES + 3) / 4, 256, 0, stream>>>(Ab, P0, P0, off, csr_src, csr_w,
                                                  h2, 2.0f, -1.0f);
    k_gather<<<(BATCH * 64 + 255) / 256, 256, 0, stream>>>(P0, batch_nodes, flag, out, r);
  }
}

// Round 2
// 1691.728 us; speedup vs baseline: 1.1976x; 1.1976x over previous
//
#include <hip/hip_runtime.h>
#include <hip/hip_bf16.h>

#define N_NODES 50000
#define N_EDGES 800000
#define N_REL   3
#define F_IN    256
#define CH      128
#define BATCH   4096
#define DT      0.25f

// ---------------------------------------------------------------------------
// Detect whether integer inputs are int64 (reference astype) or int32 (JAX
// default without x64). If int64, odd int32 words are all-zero high words.
// ---------------------------------------------------------------------------
__global__ void k_detect(const int* __restrict__ ei, int* __restrict__ flag) {
  int lane = threadIdx.x;           // 64 threads
  int v = ei[2 * lane + 1];         // int32 positions 1,3,...,127 (< 2E both ways)
  unsigned long long m = __ballot(v != 0);
  if (lane == 0) flag[0] = (m == 0ull) ? 1 : 0;  // 1 => int64
}

// in-degree histogram over col
__global__ void k_hist(const int* __restrict__ ei, long eoff,
                       const int* __restrict__ flag, int* __restrict__ deg) {
  int e = blockIdx.x * blockDim.x + threadIdx.x;
  if (e >= N_EDGES) return;
  int i64 = flag[0];
  long idx = eoff + e;
  int d = i64 ? ei[2 * idx] : ei[idx];   // little-endian low word
  atomicAdd(&deg[d], 1);
}

__global__ void k_dinv(const int* __restrict__ deg, float* __restrict__ dinv) {
  int i = blockIdx.x * blockDim.x + threadIdx.x;
  if (i >= N_NODES) return;
  int d = deg[i];
  dinv[i] = d > 0 ? rsqrtf((float)d) : 0.0f;
}

// single-block exclusive prefix scan of deg -> off[0..N]
__global__ void k_scan(const int* __restrict__ deg, int* __restrict__ off) {
  __shared__ int sm[1024];
  int tid = threadIdx.x;
  const int PER = (N_NODES + 1023) / 1024;   // 49
  int base = tid * PER;
  int s = 0;
  for (int i = 0; i < PER; ++i) { int idx = base + i; if (idx < N_NODES) s += deg[idx]; }
  sm[tid] = s;
  __syncthreads();
  for (int d = 1; d < 1024; d <<= 1) {
    int v = 0;
    if (tid >= d) v = sm[tid - d];
    __syncthreads();
    sm[tid] += v;
    __syncthreads();
  }
  int run = sm[tid] - s;  // exclusive prefix
  for (int i = 0; i < PER; ++i) {
    int idx = base + i;
    if (idx < N_NODES) { off[idx] = run; run += deg[idx]; }
  }
  if (tid == 1023) off[N_NODES] = run;   // == E
}

// scatter edges into CSR-by-destination slots; weight = dinv[src]*dinv[dst]
// packed as int2 {src, float_bits(w)} for single 8B metadata loads in k_prop
__global__ void k_fill(const int* __restrict__ ei, long roff, long coff,
                       const int* __restrict__ flag, const int* __restrict__ off,
                       int* __restrict__ cur, const float* __restrict__ dinv,
                       int2* __restrict__ csr) {
  int e = blockIdx.x * blockDim.x + threadIdx.x;
  if (e >= N_EDGES) return;
  int i64 = flag[0];
  long ri = roff + e, ci = coff + e;
  int s = i64 ? ei[2 * ri] : ei[ri];
  int d = i64 ? ei[2 * ci] : ei[ci];
  int pos = atomicAdd(&cur[d], 1);
  int slot = off[d] + pos;
  csr[slot] = make_int2(s, __float_as_int(dinv[s] * dinv[d]));
}

// ---------------------------------------------------------------------------
// Fused phi GEMM: P0 = X*W0^T + b0, P1 = X*W1^T + b1.
// BM=64 rows, BN=256 cols (128 phi0 | 128 phi1), KC=32, 8x8 per thread.
// fp32 vector ALU (no fp32 MFMA on CDNA4).
// ---------------------------------------------------------------------------
__global__ __launch_bounds__(256) void k_phi(
    const float* __restrict__ X,
    const float* __restrict__ W0, const float* __restrict__ b0,
    const float* __restrict__ W1, const float* __restrict__ b1,
    float* __restrict__ P0, float* __restrict__ P1) {
  __shared__ float As[32][64];    // [k][m]
  __shared__ float Bs[32][256];   // [k][n]
  int tid = threadIdx.x;
  int m0 = blockIdx.x * 64;
  int tc = tid & 31, tr = tid >> 5;      // tc 0..31 (n), tr 0..7 (m)
  int ml = tid & 63, j0 = tid >> 6;      // A-load mapping
  int nB = tid;                          // B-load row (0..255)
  const float* Wrow = (nB < 128) ? (W0 + (size_t)nB * F_IN)
                                 : (W1 + (size_t)(nB - 128) * F_IN);
  float acc[8][8] = {};
  for (int k0 = 0; k0 < F_IN; k0 += 32) {
#pragma unroll
    for (int t = 0; t < 2; ++t) {
      int j = j0 + 4 * t;                // 0..7 float4 along k
      int m = m0 + ml;
      float4 v = make_float4(0.f, 0.f, 0.f, 0.f);
      if (m < N_NODES) v = *(const float4*)(X + (size_t)m * F_IN + k0 + 4 * j);
      As[4 * j + 0][ml] = v.x; As[4 * j + 1][ml] = v.y;
      As[4 * j + 2][ml] = v.z; As[4 * j + 3][ml] = v.w;
    }
#pragma unroll
    for (int j = 0; j < 8; ++j) {
      float4 v = *(const float4*)(Wrow + k0 + 4 * j);
      Bs[4 * j + 0][nB] = v.x; Bs[4 * j + 1][nB] = v.y;
      Bs[4 * j + 2][nB] = v.z; Bs[4 * j + 3][nB] = v.w;
    }
    __syncthreads();
#pragma unroll
    for (int k = 0; k < 32; ++k) {
      float a[8], b[8];
      *(float4*)&a[0] = *(const float4*)&As[k][tr * 8];
      *(float4*)&a[4] = *(const float4*)&As[k][tr * 8 + 4];
      *(float4*)&b[0] = *(const float4*)&Bs[k][tc * 8];
      *(float4*)&b[4] = *(const float4*)&Bs[k][tc * 8 + 4];
#pragma unroll
      for (int i = 0; i < 8; ++i)
#pragma unroll
        for (int j = 0; j < 8; ++j) acc[i][j] = fmaf(a[i], b[j], acc[i][j]);
    }
    __syncthreads();
  }
  // epilogue: cols 0..127 -> P0, 128..255 -> P1, + bias
  const float* bp = (tc < 16) ? b0 : b1;
  float* P = (tc < 16) ? P0 : P1;
  int cb = (tc & 15) * 8;
  float bias[8];
#pragma unroll
  for (int j = 0; j < 8; ++j) bias[j] = bp[cb + j];
#pragma unroll
  for (int i = 0; i < 8; ++i) {
    int m = m0 + tr * 8 + i;
    if (m < N_NODES) {
      float4 o0 = make_float4(acc[i][0] + bias[0], acc[i][1] + bias[1],
                              acc[i][2] + bias[2], acc[i][3] + bias[3]);
      float4 o1 = make_float4(acc[i][4] + bias[4], acc[i][5] + bias[5],
                              acc[i][6] + bias[6], acc[i][7] + bias[7]);
      *(float4*)(P + (size_t)m * CH + cb) = o0;
      *(float4*)(P + (size_t)m * CH + cb + 4) = o1;
    }
  }
}

// ---------------------------------------------------------------------------
// out[i] = wscale * sum_e w[e]*xc[src[e]]  +  aself*xc[i]  +  beta*other[i]
// One wave per dst node. Lanes = 4 edge-groups x 16 channel-lanes; each lane
// loads float4 (16B). 8 edges in flight per iteration -> 4 outstanding 16B
// gathers + 2x 8B metadata loads per lane. Cross-group shfl_xor reduce.
// other/out may alias elementwise (read-before-write by same thread).
// ---------------------------------------------------------------------------
__global__ __launch_bounds__(256) void k_prop(
    const float* __restrict__ xc, const float* __restrict__ other,
    float* __restrict__ out,
    const int* __restrict__ off, const int2* __restrict__ csr,
    float wscale, float aself, float beta) {
  int node = blockIdx.x * 4 + (threadIdx.x >> 6);
  if (node >= N_NODES) return;
  int lane = threadIdx.x & 63;
  int g = lane >> 4;        // edge slot 0..3
  int l = lane & 15;        // channel slot 0..15
  int e0 = off[node], e1 = off[node + 1];
  float4 acc0 = make_float4(0.f, 0.f, 0.f, 0.f);
  float4 acc1 = make_float4(0.f, 0.f, 0.f, 0.f);
  for (int e = e0; e < e1; e += 8) {
    int eA = e + g, eB = e + 4 + g;
    int sA = 0, sB = 0;
    float wA = 0.f, wB = 0.f;
    if (eA < e1) { int2 p = csr[eA]; sA = p.x; wA = __int_as_float(p.y); }
    if (eB < e1) { int2 p = csr[eB]; sB = p.x; wB = __int_as_float(p.y); }
    const float4* rA = (const float4*)(xc + (size_t)sA * CH);
    const float4* rB = (const float4*)(xc + (size_t)sB * CH);
    float4 a0 = rA[l];
    float4 a1 = rA[l + 16];
    float4 b0 = rB[l];
    float4 b1 = rB[l + 16];
    acc0.x = fmaf(wA, a0.x, acc0.x); acc0.y = fmaf(wA, a0.y, acc0.y);
    acc0.z = fmaf(wA, a0.z, acc0.z); acc0.w = fmaf(wA, a0.w, acc0.w);
    acc1.x = fmaf(wA, a1.x, acc1.x); acc1.y = fmaf(wA, a1.y, acc1.y);
    acc1.z = fmaf(wA, a1.z, acc1.z); acc1.w = fmaf(wA, a1.w, acc1.w);
    acc0.x = fmaf(wB, b0.x, acc0.x); acc0.y = fmaf(wB, b0.y, acc0.y);
    acc0.z = fmaf(wB, b0.z, acc0.z); acc0.w = fmaf(wB, b0.w, acc0.w);
    acc1.x = fmaf(wB, b1.x, acc1.x); acc1.y = fmaf(wB, b1.y, acc1.y);
    acc1.z = fmaf(wB, b1.z, acc1.z); acc1.w = fmaf(wB, b1.w, acc1.w);
  }
  // reduce across the 4 edge-groups (lane bits 4 and 5)
#pragma unroll
  for (int m = 16; m < 64; m <<= 1) {
    acc0.x += __shfl_xor(acc0.x, m); acc0.y += __shfl_xor(acc0.y, m);
    acc0.z += __shfl_xor(acc0.z, m); acc0.w += __shfl_xor(acc0.w, m);
    acc1.x += __shfl_xor(acc1.x, m); acc1.y += __shfl_xor(acc1.y, m);
    acc1.z += __shfl_xor(acc1.z, m); acc1.w += __shfl_xor(acc1.w, m);
  }
  size_t base = (size_t)node * CH;
  if (g == 0) {
    float4 sv = *(const float4*)(xc + base + 4 * l);
    float4 ov = *(const float4*)(other + base + 4 * l);
    float4 o;
    o.x = wscale * acc0.x + aself * sv.x + beta * ov.x;
    o.y = wscale * acc0.y + aself * sv.y + beta * ov.y;
    o.z = wscale * acc0.z + aself * sv.z + beta * ov.z;
    o.w = wscale * acc0.w + aself * sv.w + beta * ov.w;
    *(float4*)(out + base + 4 * l) = o;
  } else if (g == 1) {
    float4 sv = *(const float4*)(xc + base + 64 + 4 * l);
    float4 ov = *(const float4*)(other + base + 64 + 4 * l);
    float4 o;
    o.x = wscale * acc1.x + aself * sv.x + beta * ov.x;
    o.y = wscale * acc1.y + aself * sv.y + beta * ov.y;
    o.z = wscale * acc1.z + aself * sv.z + beta * ov.z;
    o.w = wscale * acc1.w + aself * sv.w + beta * ov.w;
    *(float4*)(out + base + 64 + 4 * l) = o;
  }
}

__global__ void k_gather(const float* __restrict__ x, const int* __restrict__ batch,
                         const int* __restrict__ flag, float* __restrict__ out, int r) {
  int idx = blockIdx.x * blockDim.x + threadIdx.x;
  int b = idx >> 6, lane = idx & 63;
  if (b >= BATCH) return;
  int i64 = flag[0];
  int node = i64 ? batch[2 * b] : batch[b];
  ((float2*)out)[(size_t)b * (N_REL * 64) + r * 64 + lane] =
      ((const float2*)x)[(size_t)node * 64 + lane];
}

extern "C" void kernel_launch(void* const* d_in, const int* in_sizes, int n_in,
                              void* d_out, int out_size, void* d_ws, size_t ws_size,
                              hipStream_t stream) {
  const float* features   = (const float*)d_in[0];
  const int*   edge_index = (const int*)d_in[1];
  const int*   batch_nodes= (const int*)d_in[2];
  const float* lin0_w     = (const float*)d_in[3];
  const float* lin0_b     = (const float*)d_in[4];
  const float* lin1_w     = (const float*)d_in[5];
  const float* lin1_b     = (const float*)d_in[6];
  float* out = (float*)d_out;

  char* w = (char*)d_ws;
  size_t o = 0;
  auto nxt = [&](size_t bytes) {
    char* p = w + o;
    o = (o + bytes + 255) & ~(size_t)255;
    return p;
  };
  int*   flag    = (int*)  nxt(256);
  int*   deg     = (int*)  nxt((size_t)N_NODES * 4);
  int*   cur     = (int*)  nxt((size_t)N_NODES * 4);
  float* dinv    = (float*)nxt((size_t)N_NODES * 4);
  int*   off     = (int*)  nxt((size_t)(N_NODES + 1) * 4);
  int2*  csr     = (int2*) nxt((size_t)N_EDGES * 8);
  float* P0      = (float*)nxt((size_t)N_NODES * CH * 4);
  float* P1      = (float*)nxt((size_t)N_NODES * CH * 4);
  float* Ab      = (float*)nxt((size_t)N_NODES * CH * 4);

  k_detect<<<1, 64, 0, stream>>>(edge_index, flag);

  const float h2 = DT * DT;
  for (int r = 0; r < N_REL; ++r) {
    long roff = (long)r * 2 * N_EDGES;
    long coff = roff + N_EDGES;
    hipMemsetAsync(deg, 0, (size_t)N_NODES * 4, stream);
    hipMemsetAsync(cur, 0, (size_t)N_NODES * 4, stream);
    k_hist<<<(N_EDGES + 255) / 256, 256, 0, stream>>>(edge_index, coff, flag, deg);
    k_dinv<<<(N_NODES + 255) / 256, 256, 0, stream>>>(deg, dinv);
    k_scan<<<1, 1024, 0, stream>>>(deg, off);
    k_fill<<<(N_EDGES + 255) / 256, 256, 0, stream>>>(edge_index, roff, coff, flag,
                                                      off, cur, dinv, csr);
    k_phi<<<(N_NODES + 63) / 64, 256, 0, stream>>>(
        features, lin0_w + (size_t)r * CH * F_IN, lin0_b + (size_t)r * CH,
        lin1_w + (size_t)r * CH * F_IN, lin1_b + (size_t)r * CH, P0, P1);
    // init: x1 = dt*phi1 + (dt^2/2)*A_hat*phi0 + phi0         -> Ab
    k_prop<<<(N_NODES + 3) / 4, 256, 0, stream>>>(P0, P1, Ab, off, csr,
                                                  0.5f * h2, 1.0f, DT);
    // steps: xn = dt^2*A_hat*xc + 2*xc - xp   (3 steps, 2-buffer rotation)
    k_prop<<<(N_NODES + 3) / 4, 256, 0, stream>>>(Ab, P0, P0, off, csr,
                                                  h2, 2.0f, -1.0f);
    k_prop<<<(N_NODES + 3) / 4, 256, 0, stream>>>(P0, Ab, Ab, off, csr,
                                                  h2, 2.0f, -1.0f);
    k_prop<<<(N_NODES + 3) / 4, 256, 0, stream>>>(Ab, P0, P0, off, csr,
                                                  h2, 2.0f, -1.0f);
    k_gather<<<(BATCH * 64 + 255) / 256, 256, 0, stream>>>(P0, batch_nodes, flag, out, r);
  }
}

// Round 3
// 1322.957 us; speedup vs baseline: 1.5314x; 1.2787x over previous
//
#include <hip/hip_runtime.h>
#include <hip/hip_bf16.h>

#define N_NODES 50000
#define N_EDGES 800000
#define N_REL   3
#define F_IN    256
#define CH      128
#define BATCH   4096
#define DT      0.25f

typedef __bf16 bf16x8 __attribute__((ext_vector_type(8)));
typedef float f32x4 __attribute__((ext_vector_type(4)));

__device__ __forceinline__ ushort f2bf(float f) {
  unsigned u = __float_as_uint(f);
  return (ushort)((u + 0x7FFFu + ((u >> 16) & 1u)) >> 16);  // RNE
}
__device__ __forceinline__ float bf2f(ushort h) {
  return __uint_as_float((unsigned)h << 16);
}

// ---------------------------------------------------------------------------
// int64-vs-int32 detection for integer inputs.
// ---------------------------------------------------------------------------
__global__ void k_detect(const int* __restrict__ ei, int* __restrict__ flag) {
  int lane = threadIdx.x;           // 64 threads
  int v = ei[2 * lane + 1];
  unsigned long long m = __ballot(v != 0);
  if (lane == 0) flag[0] = (m == 0ull) ? 1 : 0;  // 1 => int64
}

// in-degree histogram over col, all 3 relations (blockIdx.y = r)
__global__ void k_hist3(const int* __restrict__ ei, const int* __restrict__ flag,
                        int* __restrict__ deg3) {
  int e = blockIdx.x * 256 + threadIdx.x;
  int r = blockIdx.y;
  if (e >= N_EDGES) return;
  long ci = (long)r * 2 * N_EDGES + N_EDGES + e;
  int d = flag[0] ? ei[2 * ci] : ei[ci];
  atomicAdd(&deg3[r * N_NODES + d], 1);
}

__global__ void k_dinv3(const int* __restrict__ deg3, float* __restrict__ dinv3) {
  int i = blockIdx.x * blockDim.x + threadIdx.x;
  if (i >= 3 * N_NODES) return;
  int d = deg3[i];
  dinv3[i] = d > 0 ? rsqrtf((float)d) : 0.0f;
}

// 3 independent single-block exclusive scans (blockIdx.x = r)
__global__ void k_scan3(const int* __restrict__ deg3, int* __restrict__ off3) {
  __shared__ int sm[1024];
  const int* deg = deg3 + blockIdx.x * N_NODES;
  int* off = off3 + blockIdx.x * (N_NODES + 1);
  int tid = threadIdx.x;
  const int PER = (N_NODES + 1023) / 1024;   // 49
  int base = tid * PER;
  int s = 0;
  for (int i = 0; i < PER; ++i) { int idx = base + i; if (idx < N_NODES) s += deg[idx]; }
  sm[tid] = s;
  __syncthreads();
  for (int d = 1; d < 1024; d <<= 1) {
    int v = 0;
    if (tid >= d) v = sm[tid - d];
    __syncthreads();
    sm[tid] += v;
    __syncthreads();
  }
  int run = sm[tid] - s;
  for (int i = 0; i < PER; ++i) {
    int idx = base + i;
    if (idx < N_NODES) { off[idx] = run; run += deg[idx]; }
  }
  if (tid == 1023) off[N_NODES] = run;
}

// CSR fill, all 3 relations (blockIdx.y = r); csr entry = {src, bits(w)}
__global__ void k_fill3(const int* __restrict__ ei, const int* __restrict__ flag,
                        const int* __restrict__ off3, int* __restrict__ cur3,
                        const float* __restrict__ dinv3, int2* __restrict__ csr) {
  int e = blockIdx.x * 256 + threadIdx.x;
  int r = blockIdx.y;
  if (e >= N_EDGES) return;
  int i64 = flag[0];
  long ri = (long)r * 2 * N_EDGES + e;
  long ci = ri + N_EDGES;
  int s = i64 ? ei[2 * ri] : ei[ri];
  int d = i64 ? ei[2 * ci] : ei[ci];
  const float* dinv = dinv3 + r * N_NODES;
  int pos = atomicAdd(&cur3[r * N_NODES + d], 1);
  int slot = off3[r * (N_NODES + 1) + d] + pos;
  csr[(size_t)r * N_EDGES + slot] = make_int2(s, __float_as_int(dinv[s] * dinv[d]));
}

// ---------------------------------------------------------------------------
// Split-precision bf16 MFMA GEMM: P = X[50000x256] * W^T[256x128] + b.
// grid (391, 2): blockIdx.y=0 -> W0/b0/P0, =1 -> W1/b1/P1.
// BM=128, BN=128, BK=32; 4 waves, each 64x64 (4x4 16x16 frags).
// x = xh + xl (bf16 RNE split), w = wh + wl; acc += xh*wh + xh*wl + xl*wh.
// LDS [row][k] ushort, 64B row stride -> b128 reads naturally bank-balanced.
// ---------------------------------------------------------------------------
__global__ __launch_bounds__(256) void k_phi_mfma(
    const float* __restrict__ X, const float* __restrict__ W0,
    const float* __restrict__ b0, const float* __restrict__ W1,
    const float* __restrict__ b1, float* __restrict__ P0,
    float* __restrict__ P1) {
  __shared__ ushort Ah[128 * 32], Al[128 * 32], Bh[128 * 32], Bl[128 * 32];
  const int tid = threadIdx.x;
  const int m0 = blockIdx.x * 128;
  const float* W = blockIdx.y ? W1 : W0;
  const float* bias = blockIdx.y ? b1 : b0;
  float* P = blockIdx.y ? P1 : P0;
  const int wid = tid >> 6, lane = tid & 63;
  const int wr = wid >> 1, wc = wid & 1;          // wave tile origin (64x64)
  const int lr = lane & 15, k8 = lane >> 4;       // frag row/col, k-slot
  const int rt = tid >> 1, kb = (tid & 1) * 16;   // staging: row, k-base
  const bool mok = (m0 + rt) < N_NODES;
  const float* Xrow = X + (size_t)(m0 + rt) * F_IN;
  const float* Wrow = W + (size_t)rt * F_IN;
  f32x4 acc[4][4] = {};
  for (int k0 = 0; k0 < F_IN; k0 += 32) {
    float4 xa[4], wb[4];
#pragma unroll
    for (int j = 0; j < 4; ++j) {
      xa[j] = mok ? *(const float4*)(Xrow + k0 + kb + 4 * j)
                  : make_float4(0.f, 0.f, 0.f, 0.f);
      wb[j] = *(const float4*)(Wrow + k0 + kb + 4 * j);
    }
    if (k0) __syncthreads();   // previous iteration's reads complete
#pragma unroll
    for (int j = 0; j < 4; ++j) {
      int idx = rt * 32 + kb + 4 * j;
      ushort h0 = f2bf(xa[j].x), h1 = f2bf(xa[j].y), h2 = f2bf(xa[j].z), h3 = f2bf(xa[j].w);
      *(ushort4*)&Ah[idx] = make_ushort4(h0, h1, h2, h3);
      *(ushort4*)&Al[idx] =
          make_ushort4(f2bf(xa[j].x - bf2f(h0)), f2bf(xa[j].y - bf2f(h1)),
                       f2bf(xa[j].z - bf2f(h2)), f2bf(xa[j].w - bf2f(h3)));
      ushort g0 = f2bf(wb[j].x), g1 = f2bf(wb[j].y), g2 = f2bf(wb[j].z), g3 = f2bf(wb[j].w);
      *(ushort4*)&Bh[idx] = make_ushort4(g0, g1, g2, g3);
      *(ushort4*)&Bl[idx] =
          make_ushort4(f2bf(wb[j].x - bf2f(g0)), f2bf(wb[j].y - bf2f(g1)),
                       f2bf(wb[j].z - bf2f(g2)), f2bf(wb[j].w - bf2f(g3)));
    }
    __syncthreads();
    bf16x8 ah[4], al[4], bh[4], bl[4];
#pragma unroll
    for (int i = 0; i < 4; ++i) {
      int ao = (wr * 64 + i * 16 + lr) * 32 + k8 * 8;
      int bo = (wc * 64 + i * 16 + lr) * 32 + k8 * 8;
      ah[i] = *(const bf16x8*)&Ah[ao];
      al[i] = *(const bf16x8*)&Al[ao];
      bh[i] = *(const bf16x8*)&Bh[bo];
      bl[i] = *(const bf16x8*)&Bl[bo];
    }
#pragma unroll
    for (int i = 0; i < 4; ++i)
#pragma unroll
      for (int j = 0; j < 4; ++j) {
        acc[i][j] = __builtin_amdgcn_mfma_f32_16x16x32_bf16(ah[i], bh[j], acc[i][j], 0, 0, 0);
        acc[i][j] = __builtin_amdgcn_mfma_f32_16x16x32_bf16(ah[i], bl[j], acc[i][j], 0, 0, 0);
        acc[i][j] = __builtin_amdgcn_mfma_f32_16x16x32_bf16(al[i], bh[j], acc[i][j], 0, 0, 0);
      }
  }
  // epilogue: D frag (i,j): col = wc*64 + j*16 + lr; rows = wr*64 + i*16 + k8*4 + q
#pragma unroll
  for (int j = 0; j < 4; ++j) {
    int ch = wc * 64 + j * 16 + lr;
    float bv = bias[ch];
#pragma unroll
    for (int i = 0; i < 4; ++i) {
      int mbase = m0 + wr * 64 + i * 16 + k8 * 4;
#pragma unroll
      for (int q = 0; q < 4; ++q) {
        int m = mbase + q;
        if (m < N_NODES) P[(size_t)m * CH + ch] = acc[i][j][q] + bv;
      }
    }
  }
}

// ---------------------------------------------------------------------------
// out[i] = wscale * sum_e w[e]*xc[src[e]] + aself*xc[i] + beta*other[i]
// One wave per dst node; 4 edge-groups x 16 channel-lanes; 16 edges in
// flight (8 float4 + 4 int2 outstanding per lane). VGPR-capped for ~6
// waves/SIMD. other/out alias elementwise (read-before-write, same thread).
// ---------------------------------------------------------------------------
__global__ __launch_bounds__(256, 6) void k_prop(
    const float* __restrict__ xc, const float* __restrict__ other,
    float* __restrict__ out, const int* __restrict__ off,
    const int2* __restrict__ csr, float wscale, float aself, float beta) {
  int node = blockIdx.x * 4 + (threadIdx.x >> 6);
  if (node >= N_NODES) return;
  int lane = threadIdx.x & 63;
  int g = lane >> 4, l = lane & 15;
  int e0 = off[node], e1 = off[node + 1];
  size_t base = (size_t)node * CH;
  int go = (g & 1) * 64;
  float4 sv = *(const float4*)(xc + base + go + 4 * l);      // issued early
  float4 ov = *(const float4*)(other + base + go + 4 * l);
  float4 acc0 = make_float4(0.f, 0.f, 0.f, 0.f);
  float4 acc1 = make_float4(0.f, 0.f, 0.f, 0.f);
  for (int e = e0; e < e1; e += 16) {
    int lim = e1 - 1;                 // loop entered => e1 > e0 => lim >= e0
    int2 pm[4];
    float wgt[4];
#pragma unroll
    for (int u = 0; u < 4; ++u) {
      int ee = e + 4 * u + g;
      pm[u] = csr[min(ee, lim)];
      wgt[u] = (ee <= lim) ? __int_as_float(pm[u].y) : 0.f;
    }
    float4 va[4], vb[4];
#pragma unroll
    for (int u = 0; u < 4; ++u) {
      const float4* rs = (const float4*)(xc + (size_t)pm[u].x * CH);
      va[u] = rs[l];
      vb[u] = rs[l + 16];
    }
#pragma unroll
    for (int u = 0; u < 4; ++u) {
      float w0 = wgt[u];
      acc0.x = fmaf(w0, va[u].x, acc0.x); acc0.y = fmaf(w0, va[u].y, acc0.y);
      acc0.z = fmaf(w0, va[u].z, acc0.z); acc0.w = fmaf(w0, va[u].w, acc0.w);
      acc1.x = fmaf(w0, vb[u].x, acc1.x); acc1.y = fmaf(w0, vb[u].y, acc1.y);
      acc1.z = fmaf(w0, vb[u].z, acc1.z); acc1.w = fmaf(w0, vb[u].w, acc1.w);
    }
  }
#pragma unroll
  for (int m = 16; m < 64; m <<= 1) {
    acc0.x += __shfl_xor(acc0.x, m); acc0.y += __shfl_xor(acc0.y, m);
    acc0.z += __shfl_xor(acc0.z, m); acc0.w += __shfl_xor(acc0.w, m);
    acc1.x += __shfl_xor(acc1.x, m); acc1.y += __shfl_xor(acc1.y, m);
    acc1.z += __shfl_xor(acc1.z, m); acc1.w += __shfl_xor(acc1.w, m);
  }
  if (g == 0) {
    float4 o;
    o.x = wscale * acc0.x + aself * sv.x + beta * ov.x;
    o.y = wscale * acc0.y + aself * sv.y + beta * ov.y;
    o.z = wscale * acc0.z + aself * sv.z + beta * ov.z;
    o.w = wscale * acc0.w + aself * sv.w + beta * ov.w;
    *(float4*)(out + base + 4 * l) = o;
  } else if (g == 1) {
    float4 o;
    o.x = wscale * acc1.x + aself * sv.x + beta * ov.x;
    o.y = wscale * acc1.y + aself * sv.y + beta * ov.y;
    o.z = wscale * acc1.z + aself * sv.z + beta * ov.z;
    o.w = wscale * acc1.w + aself * sv.w + beta * ov.w;
    *(float4*)(out + base + 64 + 4 * l) = o;
  }
}

__global__ void k_gather(const float* __restrict__ x, const int* __restrict__ batch,
                         const int* __restrict__ flag, float* __restrict__ out, int r) {
  int idx = blockIdx.x * blockDim.x + threadIdx.x;
  int b = idx >> 6, lane = idx & 63;
  if (b >= BATCH) return;
  int i64 = flag[0];
  int node = i64 ? batch[2 * b] : batch[b];
  ((float2*)out)[(size_t)b * (N_REL * 64) + r * 64 + lane] =
      ((const float2*)x)[(size_t)node * 64 + lane];
}

extern "C" void kernel_launch(void* const* d_in, const int* in_sizes, int n_in,
                              void* d_out, int out_size, void* d_ws, size_t ws_size,
                              hipStream_t stream) {
  const float* features   = (const float*)d_in[0];
  const int*   edge_index = (const int*)d_in[1];
  const int*   batch_nodes= (const int*)d_in[2];
  const float* lin0_w     = (const float*)d_in[3];
  const float* lin0_b     = (const float*)d_in[4];
  const float* lin1_w     = (const float*)d_in[5];
  const float* lin1_b     = (const float*)d_in[6];
  float* out = (float*)d_out;

  char* w = (char*)d_ws;
  size_t o = 0;
  auto nxt = [&](size_t bytes) {
    char* p = w + o;
    o = (o + bytes + 255) & ~(size_t)255;
    return p;
  };
  int*   flag  = (int*)  nxt(256);
  int*   deg3  = (int*)  nxt((size_t)3 * N_NODES * 4);
  int*   cur3  = (int*)  nxt((size_t)3 * N_NODES * 4);
  float* dinv3 = (float*)nxt((size_t)3 * N_NODES * 4);
  int*   off3  = (int*)  nxt((size_t)3 * (N_NODES + 1) * 4);
  int2*  csr   = (int2*) nxt((size_t)3 * N_EDGES * 8);
  float* P0    = (float*)nxt((size_t)N_NODES * CH * 4);
  float* P1    = (float*)nxt((size_t)N_NODES * CH * 4);
  float* Ab    = (float*)nxt((size_t)N_NODES * CH * 4);

  k_detect<<<1, 64, 0, stream>>>(edge_index, flag);
  hipMemsetAsync(deg3, 0, (size_t)3 * N_NODES * 4, stream);
  hipMemsetAsync(cur3, 0, (size_t)3 * N_NODES * 4, stream);
  k_hist3<<<dim3((N_EDGES + 255) / 256, 3), 256, 0, stream>>>(edge_index, flag, deg3);
  k_dinv3<<<(3 * N_NODES + 255) / 256, 256, 0, stream>>>(deg3, dinv3);
  k_scan3<<<3, 1024, 0, stream>>>(deg3, off3);
  k_fill3<<<dim3((N_EDGES + 255) / 256, 3), 256, 0, stream>>>(edge_index, flag, off3,
                                                              cur3, dinv3, csr);

  const float h2 = DT * DT;
  for (int r = 0; r < N_REL; ++r) {
    const int*  offr = off3 + r * (N_NODES + 1);
    const int2* csrr = csr + (size_t)r * N_EDGES;
    k_phi_mfma<<<dim3((N_NODES + 127) / 128, 2), 256, 0, stream>>>(
        features, lin0_w + (size_t)r * CH * F_IN, lin0_b + (size_t)r * CH,
        lin1_w + (size_t)r * CH * F_IN, lin1_b + (size_t)r * CH, P0, P1);
    // init: x1 = dt*phi1 + (dt^2/2)*A_hat*phi0 + phi0         -> Ab
    k_prop<<<(N_NODES + 3) / 4, 256, 0, stream>>>(P0, P1, Ab, offr, csrr,
                                                  0.5f * h2, 1.0f, DT);
    // steps: xn = dt^2*A_hat*xc + 2*xc - xp   (3 steps, 2-buffer rotation)
    k_prop<<<(N_NODES + 3) / 4, 256, 0, stream>>>(Ab, P0, P0, offr, csrr,
                                                  h2, 2.0f, -1.0f);
    k_prop<<<(N_NODES + 3) / 4, 256, 0, stream>>>(P0, Ab, Ab, offr, csrr,
                                                  h2, 2.0f, -1.0f);
    k_prop<<<(N_NODES + 3) / 4, 256, 0, stream>>>(Ab, P0, P0, offr, csrr,
                                                  h2, 2.0f, -1.0f);
    k_gather<<<(BATCH * 64 + 255) / 256, 256, 0, stream>>>(P0, batch_nodes, flag, out, r);
  }
}

// Round 7
// 1189.781 us; speedup vs baseline: 1.7028x; 1.1119x over previous
//
#include <hip/hip_runtime.h>
#include <hip/hip_bf16.h>

#define N_NODES 50000
#define N_EDGES 800000
#define N_REL   3
#define F_IN    256
#define CH      128
#define BATCH   4096
#define DT      0.25f

typedef __bf16 bf16x8 __attribute__((ext_vector_type(8)));
typedef float f32x4 __attribute__((ext_vector_type(4)));

__device__ __forceinline__ ushort f2bf(float f) {
  unsigned u = __float_as_uint(f);
  return (ushort)((u + 0x7FFFu + ((u >> 16) & 1u)) >> 16);  // RNE
}
__device__ __forceinline__ float bf2f(ushort h) {
  return __uint_as_float((unsigned)h << 16);
}

// flag[0] = inputs are int64 (vs int32); flag[1] = some node has in-degree 0
__global__ void k_detect(const int* __restrict__ ei, int* __restrict__ flag) {
  int lane = threadIdx.x;
  int v = ei[2 * lane + 1];
  unsigned long long m = __ballot(v != 0);
  if (lane == 0) flag[0] = (m == 0ull) ? 1 : 0;
}

__global__ void k_hist3(const int* __restrict__ ei, const int* __restrict__ flag,
                        int* __restrict__ deg3) {
  int e = blockIdx.x * 256 + threadIdx.x;
  int r = blockIdx.y;
  if (e >= N_EDGES) return;
  long ci = (long)r * 2 * N_EDGES + N_EDGES + e;
  int d = flag[0] ? ei[2 * ci] : ei[ci];
  atomicAdd(&deg3[r * N_NODES + d], 1);
}

__global__ void k_dinv3(const int* __restrict__ deg3, float* __restrict__ dinv3,
                        int* __restrict__ flag) {
  int i = blockIdx.x * blockDim.x + threadIdx.x;
  if (i >= 3 * N_NODES) return;
  int d = deg3[i];
  if (d > 0) {
    dinv3[i] = rsqrtf((float)d);
  } else {
    dinv3[i] = 0.0f;
    atomicOr(&flag[1], 1);
  }
}

__global__ void k_scan3(const int* __restrict__ deg3, int* __restrict__ off3) {
  __shared__ int sm[1024];
  const int* deg = deg3 + blockIdx.x * N_NODES;
  int* off = off3 + blockIdx.x * (N_NODES + 1);
  int tid = threadIdx.x;
  const int PER = (N_NODES + 1023) / 1024;
  int base = tid * PER;
  int s = 0;
  for (int i = 0; i < PER; ++i) { int idx = base + i; if (idx < N_NODES) s += deg[idx]; }
  sm[tid] = s;
  __syncthreads();
  for (int d = 1; d < 1024; d <<= 1) {
    int v = 0;
    if (tid >= d) v = sm[tid - d];
    __syncthreads();
    sm[tid] += v;
    __syncthreads();
  }
  int run = sm[tid] - s;
  for (int i = 0; i < PER; ++i) {
    int idx = base + i;
    if (idx < N_NODES) { off[idx] = run; run += deg[idx]; }
  }
  if (tid == 1023) off[N_NODES] = run;
}

// Fast path: 4B src-only CSR (weight==1 in y-space). Slow: int2 {src, w}.
__global__ void k_fill3(const int* __restrict__ ei, const int* __restrict__ flag,
                        const int* __restrict__ off3, int* __restrict__ cur3,
                        const float* __restrict__ dinv3, void* __restrict__ csrv) {
  int e = blockIdx.x * 256 + threadIdx.x;
  int r = blockIdx.y;
  if (e >= N_EDGES) return;
  int i64 = flag[0], iso = flag[1];
  long ri = (long)r * 2 * N_EDGES + e;
  long ci = ri + N_EDGES;
  int s = i64 ? ei[2 * ri] : ei[ri];
  int d = i64 ? ei[2 * ci] : ei[ci];
  int pos = atomicAdd(&cur3[r * N_NODES + d], 1);
  int slot = off3[r * (N_NODES + 1) + d] + pos;
  if (iso) {
    const float* dinv = dinv3 + r * N_NODES;
    ((int2*)csrv)[(size_t)r * N_EDGES + slot] =
        make_int2(s, __float_as_int(dinv[s] * dinv[d]));
  } else {
    ((int*)csrv)[(size_t)r * N_EDGES + slot] = s;
  }
}

__global__ __launch_bounds__(256) void k_phi_mfma(
    const float* __restrict__ X, const float* __restrict__ W0,
    const float* __restrict__ b0, const float* __restrict__ W1,
    const float* __restrict__ b1, const float* __restrict__ dinv,
    const int* __restrict__ flag, float* __restrict__ P0,
    float* __restrict__ P1) {
  __shared__ ushort Ah[128 * 32], Al[128 * 32], Bh[128 * 32], Bl[128 * 32];
  const int tid = threadIdx.x;
  const int m0 = blockIdx.x * 128;
  const float* W = blockIdx.y ? W1 : W0;
  const float* bias = blockIdx.y ? b1 : b0;
  float* P = blockIdx.y ? P1 : P0;
  const int wid = tid >> 6, lane = tid & 63;
  const int wr = wid >> 1, wc = wid & 1;
  const int lr = lane & 15, k8 = lane >> 4;
  const int rt = tid >> 1, kb = (tid & 1) * 16;
  const bool mok = (m0 + rt) < N_NODES;
  const float* Xrow = X + (size_t)(m0 + rt) * F_IN;
  const float* Wrow = W + (size_t)rt * F_IN;
  f32x4 acc[4][4] = {};
  for (int k0 = 0; k0 < F_IN; k0 += 32) {
    float4 xa[4], wb[4];
#pragma unroll
    for (int j = 0; j < 4; ++j) {
      xa[j] = mok ? *(const float4*)(Xrow + k0 + kb + 4 * j)
                  : make_float4(0.f, 0.f, 0.f, 0.f);
      wb[j] = *(const float4*)(Wrow + k0 + kb + 4 * j);
    }
    if (k0) __syncthreads();
#pragma unroll
    for (int j = 0; j < 4; ++j) {
      int idx = rt * 32 + kb + 4 * j;
      ushort h0 = f2bf(xa[j].x), h1 = f2bf(xa[j].y), h2 = f2bf(xa[j].z), h3 = f2bf(xa[j].w);
      *(ushort4*)&Ah[idx] = make_ushort4(h0, h1, h2, h3);
      *(ushort4*)&Al[idx] =
          make_ushort4(f2bf(xa[j].x - bf2f(h0)), f2bf(xa[j].y - bf2f(h1)),
                       f2bf(xa[j].z - bf2f(h2)), f2bf(xa[j].w - bf2f(h3)));
      ushort g0 = f2bf(wb[j].x), g1 = f2bf(wb[j].y), g2 = f2bf(wb[j].z), g3 = f2bf(wb[j].w);
      *(ushort4*)&Bh[idx] = make_ushort4(g0, g1, g2, g3);
      *(ushort4*)&Bl[idx] =
          make_ushort4(f2bf(wb[j].x - bf2f(g0)), f2bf(wb[j].y - bf2f(g1)),
                       f2bf(wb[j].z - bf2f(g2)), f2bf(wb[j].w - bf2f(g3)));
    }
    __syncthreads();
    bf16x8 ah[4], al[4], bh[4], bl[4];
#pragma unroll
    for (int i = 0; i < 4; ++i) {
      int ao = (wr * 64 + i * 16 + lr) * 32 + k8 * 8;
      int bo = (wc * 64 + i * 16 + lr) * 32 + k8 * 8;
      ah[i] = *(const bf16x8*)&Ah[ao];
      al[i] = *(const bf16x8*)&Al[ao];
      bh[i] = *(const bf16x8*)&Bh[bo];
      bl[i] = *(const bf16x8*)&Bl[bo];
    }
#pragma unroll
    for (int i = 0; i < 4; ++i)
#pragma unroll
      for (int j = 0; j < 4; ++j) {
        acc[i][j] = __builtin_amdgcn_mfma_f32_16x16x32_bf16(ah[i], bh[j], acc[i][j], 0, 0, 0);
        acc[i][j] = __builtin_amdgcn_mfma_f32_16x16x32_bf16(ah[i], bl[j], acc[i][j], 0, 0, 0);
        acc[i][j] = __builtin_amdgcn_mfma_f32_16x16x32_bf16(al[i], bh[j], acc[i][j], 0, 0, 0);
      }
  }
  int iso = flag[1];
  float rsc[4][4];
#pragma unroll
  for (int i = 0; i < 4; ++i)
#pragma unroll
    for (int q = 0; q < 4; ++q) {
      int m = m0 + wr * 64 + i * 16 + k8 * 4 + q;
      rsc[i][q] = (m < N_NODES && !iso) ? dinv[m] : 1.0f;
    }
#pragma unroll
  for (int j = 0; j < 4; ++j) {
    int ch = wc * 64 + j * 16 + lr;
    float bv = bias[ch];
#pragma unroll
    for (int i = 0; i < 4; ++i) {
      int mbase = m0 + wr * 64 + i * 16 + k8 * 4;
#pragma unroll
      for (int q = 0; q < 4; ++q) {
        int m = mbase + q;
        if (m < N_NODES) P[(size_t)m * CH + ch] = (acc[i][j][q] + bv) * rsc[i][q];
      }
    }
  }
}

// Shared edge-accumulate body used by k_prop / k_gprop.
__device__ __forceinline__ void prop_accum(
    const float* __restrict__ xc, const void* __restrict__ csrv, int r, int iso,
    int e0, int e1, int g, int l, float4& acc0, float4& acc1) {
  if (!iso) {
    const int* csr = (const int*)csrv + (size_t)r * N_EDGES;
    for (int e = e0; e < e1; e += 16) {
      int lim = e1 - 1;
      int src[4]; float wgt[4];
#pragma unroll
      for (int u = 0; u < 4; ++u) {
        int ee = e + 4 * u + g;
        src[u] = csr[min(ee, lim)];
        wgt[u] = (ee <= lim) ? 1.f : 0.f;
      }
      float4 va[4], vb[4];
#pragma unroll
      for (int u = 0; u < 4; ++u) {
        const float4* rs = (const float4*)(xc + (size_t)src[u] * CH);
        va[u] = rs[l];
        vb[u] = rs[l + 16];
      }
#pragma unroll
      for (int u = 0; u < 4; ++u) {
        float w0 = wgt[u];
        acc0.x = fmaf(w0, va[u].x, acc0.x); acc0.y = fmaf(w0, va[u].y, acc0.y);
        acc0.z = fmaf(w0, va[u].z, acc0.z); acc0.w = fmaf(w0, va[u].w, acc0.w);
        acc1.x = fmaf(w0, vb[u].x, acc1.x); acc1.y = fmaf(w0, vb[u].y, acc1.y);
        acc1.z = fmaf(w0, vb[u].z, acc1.z); acc1.w = fmaf(w0, vb[u].w, acc1.w);
      }
    }
  } else {
    const int2* csr = (const int2*)csrv + (size_t)r * N_EDGES;
    for (int e = e0; e < e1; e += 16) {
      int lim = e1 - 1;
      int2 pm[4]; float wgt[4];
#pragma unroll
      for (int u = 0; u < 4; ++u) {
        int ee = e + 4 * u + g;
        pm[u] = csr[min(ee, lim)];
        wgt[u] = (ee <= lim) ? __int_as_float(pm[u].y) : 0.f;
      }
      float4 va[4], vb[4];
#pragma unroll
      for (int u = 0; u < 4; ++u) {
        const float4* rs = (const float4*)(xc + (size_t)pm[u].x * CH);
        va[u] = rs[l];
        vb[u] = rs[l + 16];
      }
#pragma unroll
      for (int u = 0; u < 4; ++u) {
        float w0 = wgt[u];
        acc0.x = fmaf(w0, va[u].x, acc0.x); acc0.y = fmaf(w0, va[u].y, acc0.y);
        acc0.z = fmaf(w0, va[u].z, acc0.z); acc0.w = fmaf(w0, va[u].w, acc0.w);
        acc1.x = fmaf(w0, vb[u].x, acc1.x); acc1.y = fmaf(w0, vb[u].y, acc1.y);
        acc1.z = fmaf(w0, vb[u].z, acc1.z); acc1.w = fmaf(w0, vb[u].w, acc1.w);
      }
    }
  }
}

__global__ __launch_bounds__(256, 6) void k_prop(
    const float* __restrict__ xc, const float* __restrict__ other,
    float* __restrict__ out, const int* __restrict__ off,
    const void* __restrict__ csrv, const int* __restrict__ flag, int r,
    float wscale, float aself, float beta) {
  int node = blockIdx.x * 4 + (threadIdx.x >> 6);
  if (node >= N_NODES) return;
  int iso = flag[1];
  int lane = threadIdx.x & 63;
  int g = lane >> 4, l = lane & 15;
  int e0 = off[node], e1 = off[node + 1];
  size_t base = (size_t)node * CH;
  int go = (g & 1) * 64;
  float4 sv = *(const float4*)(xc + base + go + 4 * l);
  float4 ov = *(const float4*)(other + base + go + 4 * l);
  float4 acc0 = make_float4(0.f, 0.f, 0.f, 0.f);
  float4 acc1 = make_float4(0.f, 0.f, 0.f, 0.f);
  prop_accum(xc, csrv, r, iso, e0, e1, g, l, acc0, acc1);
#pragma unroll
  for (int m = 16; m < 64; m <<= 1) {
    acc0.x += __shfl_xor(acc0.x, m); acc0.y += __shfl_xor(acc0.y, m);
    acc0.z += __shfl_xor(acc0.z, m); acc0.w += __shfl_xor(acc0.w, m);
    acc1.x += __shfl_xor(acc1.x, m); acc1.y += __shfl_xor(acc1.y, m);
    acc1.z += __shfl_xor(acc1.z, m); acc1.w += __shfl_xor(acc1.w, m);
  }
  float ws2 = iso ? wscale : ((e1 > e0) ? wscale / (float)(e1 - e0) : 0.f);
  if (g == 0) {
    float4 o;
    o.x = ws2 * acc0.x + aself * sv.x + beta * ov.x;
    o.y = ws2 * acc0.y + aself * sv.y + beta * ov.y;
    o.z = ws2 * acc0.z + aself * sv.z + beta * ov.z;
    o.w = ws2 * acc0.w + aself * sv.w + beta * ov.w;
    *(float4*)(out + base + 4 * l) = o;
  } else if (g == 1) {
    float4 o;
    o.x = ws2 * acc1.x + aself * sv.x + beta * ov.x;
    o.y = ws2 * acc1.y + aself * sv.y + beta * ov.y;
    o.z = ws2 * acc1.z + aself * sv.z + beta * ov.z;
    o.w = ws2 * acc1.w + aself * sv.w + beta * ov.w;
    *(float4*)(out + base + 64 + 4 * l) = o;
  }
}

__global__ __launch_bounds__(256) void k_gprop(
    const float* __restrict__ y3, const float* __restrict__ y2,
    const int* __restrict__ off, const void* __restrict__ csrv,
    const int* __restrict__ flag, const int* __restrict__ batch,
    float* __restrict__ out, int r, float wscale, float aself, float beta) {
  int b = blockIdx.x * 4 + (threadIdx.x >> 6);
  if (b >= BATCH) return;
  int i64 = flag[0], iso = flag[1];
  int node = i64 ? batch[2 * b] : batch[b];
  int lane = threadIdx.x & 63;
  int g = lane >> 4, l = lane & 15;
  int e0 = off[node], e1 = off[node + 1];
  size_t base = (size_t)node * CH;
  int go = (g & 1) * 64;
  float4 sv = *(const float4*)(y3 + base + go + 4 * l);
  float4 ov = *(const float4*)(y2 + base + go + 4 * l);
  float4 acc0 = make_float4(0.f, 0.f, 0.f, 0.f);
  float4 acc1 = make_float4(0.f, 0.f, 0.f, 0.f);
  prop_accum(y3, csrv, r, iso, e0, e1, g, l, acc0, acc1);
#pragma unroll
  for (int m = 16; m < 64; m <<= 1) {
    acc0.x += __shfl_xor(acc0.x, m); acc0.y += __shfl_xor(acc0.y, m);
    acc0.z += __shfl_xor(acc0.z, m); acc0.w += __shfl_xor(acc0.w, m);
    acc1.x += __shfl_xor(acc1.x, m); acc1.y += __shfl_xor(acc1.y, m);
    acc1.z += __shfl_xor(acc1.z, m); acc1.w += __shfl_xor(acc1.w, m);
  }
  int deg = e1 - e0;
  float ws2 = iso ? wscale : ((deg > 0) ? wscale / (float)deg : 0.f);
  float osc = iso ? 1.0f : sqrtf((float)deg);
  float* orow = out + (size_t)b * (N_REL * CH) + r * CH;
  if (g == 0) {
    float4 o;
    o.x = osc * (ws2 * acc0.x + aself * sv.x + beta * ov.x);
    o.y = osc * (ws2 * acc0.y + aself * sv.y + beta * ov.y);
    o.z = osc * (ws2 * acc0.z + aself * sv.z + beta * ov.z);
    o.w = osc * (ws2 * acc0.w + aself * sv.w + beta * ov.w);
    *(float4*)(orow + 4 * l) = o;
  } else if (g == 1) {
    float4 o;
    o.x = osc * (ws2 * acc1.x + aself * sv.x + beta * ov.x);
    o.y = osc * (ws2 * acc1.y + aself * sv.y + beta * ov.y);
    o.z = osc * (ws2 * acc1.z + aself * sv.z + beta * ov.z);
    o.w = osc * (ws2 * acc1.w + aself * sv.w + beta * ov.w);
    *(float4*)(orow + 64 + 4 * l) = o;
  }
}

extern "C" void kernel_launch(void* const* d_in, const int* in_sizes, int n_in,
                              void* d_out, int out_size, void* d_ws, size_t ws_size,
                              hipStream_t stream) {
  const float* features   = (const float*)d_in[0];
  const int*   edge_index = (const int*)d_in[1];
  const int*   batch_nodes= (const int*)d_in[2];
  const float* lin0_w     = (const float*)d_in[3];
  const float* lin0_b     = (const float*)d_in[4];
  const float* lin1_w     = (const float*)d_in[5];
  const float* lin1_b     = (const float*)d_in[6];
  float* out = (float*)d_out;

  char* w = (char*)d_ws;
  size_t o = 0;
  auto nxt = [&](size_t bytes) {
    char* p = w + o;
    o = (o + bytes + 255) & ~(size_t)255;
    return p;
  };
  int*   flag  = (int*)  nxt(256);
  int*   deg3  = (int*)  nxt((size_t)3 * N_NODES * 4);
  int*   cur3  = (int*)  nxt((size_t)3 * N_NODES * 4);
  float* dinv3 = (float*)nxt((size_t)3 * N_NODES * 4);
  int*   off3  = (int*)  nxt((size_t)3 * (N_NODES + 1) * 4);
  void*  csr   = (void*) nxt((size_t)3 * N_EDGES * 8);
  float* P0    = (float*)nxt((size_t)N_NODES * CH * 4);
  float* P1    = (float*)nxt((size_t)N_NODES * CH * 4);
  float* Ab    = (float*)nxt((size_t)N_NODES * CH * 4);

  hipMemsetAsync(flag, 0, 8, stream);
  hipMemsetAsync(deg3, 0, (size_t)3 * N_NODES * 4, stream);
  hipMemsetAsync(cur3, 0, (size_t)3 * N_NODES * 4, stream);
  k_detect<<<1, 64, 0, stream>>>(edge_index, flag);
  k_hist3<<<dim3((N_EDGES + 255) / 256, 3), 256, 0, stream>>>(edge_index, flag, deg3);
  k_dinv3<<<(3 * N_NODES + 255) / 256, 256, 0, stream>>>(deg3, dinv3, flag);
  k_scan3<<<3, 1024, 0, stream>>>(deg3, off3);
  k_fill3<<<dim3((N_EDGES + 255) / 256, 3), 256, 0, stream>>>(edge_index, flag, off3,
                                                              cur3, dinv3, csr);

  const float h2 = DT * DT;
  for (int r = 0; r < N_REL; ++r) {
    const int* offr = off3 + r * (N_NODES + 1);
    k_phi_mfma<<<dim3((N_NODES + 127) / 128, 2), 256, 0, stream>>>(
        features, lin0_w + (size_t)r * CH * F_IN, lin0_b + (size_t)r * CH,
        lin1_w + (size_t)r * CH * F_IN, lin1_b + (size_t)r * CH,
        dinv3 + r * N_NODES, flag, P0, P1);
    // q0=P0, q1=P1.  Y1 = dt*q1 + (h^2/2)*Anorm*q0 + q0   -> Ab
    k_prop<<<(N_NODES + 3) / 4, 256, 0, stream>>>(P0, P1, Ab, offr, csr, flag, r,
                                                  0.5f * h2, 1.0f, DT);
    // Y2 = h^2*Anorm*Y1 + 2*Y1 - q0   -> P0
    k_prop<<<(N_NODES + 3) / 4, 256, 0, stream>>>(Ab, P0, P0, offr, csr, flag, r,
                                                  h2, 2.0f, -1.0f);
    // Y3 = h^2*Anorm*Y2 + 2*Y2 - Y1   -> Ab
    k_prop<<<(N_NODES + 3) / 4, 256, 0, stream>>>(P0, Ab, Ab, offr, csr, flag, r,
                                                  h2, 2.0f, -1.0f);
    // Y4[batch] fused with gather (+ sqrt(deg) rescale) -> out slice r
    k_gprop<<<(BATCH + 3) / 4, 256, 0, stream>>>(Ab, P0, offr, csr, flag,
                                                 batch_nodes, out, r,
                                                 h2, 2.0f, -1.0f);
  }
}

// Round 8
// 1136.134 us; speedup vs baseline: 1.7832x; 1.0472x over previous
//
#include <hip/hip_runtime.h>
#include <hip/hip_bf16.h>

#define N_NODES 50000
#define N_EDGES 800000
#define N_REL   3
#define F_IN    256
#define CH      128
#define BATCH   4096
#define DT      0.25f
#define NRANGE  8
#define RSPAN   6250   // N_NODES / NRANGE exactly

typedef __bf16 bf16x8 __attribute__((ext_vector_type(8)));
typedef float f32x4 __attribute__((ext_vector_type(4)));

__device__ __forceinline__ ushort f2bf(float f) {
  unsigned u = __float_as_uint(f);
  return (ushort)((u + 0x7FFFu + ((u >> 16) & 1u)) >> 16);  // RNE
}
__device__ __forceinline__ float bf2f(ushort h) {
  return __uint_as_float((unsigned)h << 16);
}

// flag[0] = inputs are int64 (vs int32); flag[1] = some node has in-degree 0
__global__ void k_detect(const int* __restrict__ ei, int* __restrict__ flag) {
  int lane = threadIdx.x;
  int v = ei[2 * lane + 1];
  unsigned long long m = __ballot(v != 0);
  if (lane == 0) flag[0] = (m == 0ull) ? 1 : 0;
}

// XCD-range-pinned in-degree histogram: block b -> chunk b>>3, dst-range b&7.
// All writers of deg3 range q sit on (approximately) one XCD -> no L2 ping-pong.
__global__ void k_hist3x(const int* __restrict__ ei, const int* __restrict__ flag,
                         int* __restrict__ deg3) {
  int b = blockIdx.x;
  int q = b & (NRANGE - 1), chunk = b >> 3;
  int e = chunk * 256 + threadIdx.x;
  int r = blockIdx.y;
  if (e >= N_EDGES) return;
  long ci = (long)r * 2 * N_EDGES + N_EDGES + e;
  int d = flag[0] ? ei[2 * ci] : ei[ci];
  if (d / RSPAN == q) atomicAdd(&deg3[r * N_NODES + d], 1);
}

__global__ void k_dinv3(const int* __restrict__ deg3, float* __restrict__ dinv3,
                        int* __restrict__ flag) {
  int i = blockIdx.x * blockDim.x + threadIdx.x;
  if (i >= 3 * N_NODES) return;
  int d = deg3[i];
  if (d > 0) {
    dinv3[i] = rsqrtf((float)d);
  } else {
    dinv3[i] = 0.0f;
    atomicOr(&flag[1], 1);
  }
}

__global__ void k_scan3(const int* __restrict__ deg3, int* __restrict__ off3) {
  __shared__ int sm[1024];
  const int* deg = deg3 + blockIdx.x * N_NODES;
  int* off = off3 + blockIdx.x * (N_NODES + 1);
  int tid = threadIdx.x;
  const int PER = (N_NODES + 1023) / 1024;
  int base = tid * PER;
  int s = 0;
  for (int i = 0; i < PER; ++i) { int idx = base + i; if (idx < N_NODES) s += deg[idx]; }
  sm[tid] = s;
  __syncthreads();
  for (int d = 1; d < 1024; d <<= 1) {
    int v = 0;
    if (tid >= d) v = sm[tid - d];
    __syncthreads();
    sm[tid] += v;
    __syncthreads();
  }
  int run = sm[tid] - s;
  for (int i = 0; i < PER; ++i) {
    int idx = base + i;
    if (idx < N_NODES) { off[idx] = run; run += deg[idx]; }
  }
  if (tid == 1023) off[N_NODES] = run;
}

// XCD-range-pinned CSR fill. Fast path: 4B src-only entries (y-space,
// weight==1). Slow path (isolated nodes exist): int2 {src, w}.
__global__ void k_fill3x(const int* __restrict__ ei, const int* __restrict__ flag,
                         const int* __restrict__ off3, int* __restrict__ cur3,
                         const float* __restrict__ dinv3, void* __restrict__ csrv) {
  int b = blockIdx.x;
  int q = b & (NRANGE - 1), chunk = b >> 3;
  int e = chunk * 256 + threadIdx.x;
  int r = blockIdx.y;
  if (e >= N_EDGES) return;
  int i64 = flag[0], iso = flag[1];
  long ri = (long)r * 2 * N_EDGES + e;
  long ci = ri + N_EDGES;
  int d = i64 ? ei[2 * ci] : ei[ci];
  if (d / RSPAN != q) return;
  int s = i64 ? ei[2 * ri] : ei[ri];
  int pos = atomicAdd(&cur3[r * N_NODES + d], 1);
  int slot = off3[r * (N_NODES + 1) + d] + pos;
  if (iso) {
    const float* dinv = dinv3 + r * N_NODES;
    ((int2*)csrv)[(size_t)r * N_EDGES + slot] =
        make_int2(s, __float_as_int(dinv[s] * dinv[d]));
  } else {
    ((int*)csrv)[(size_t)r * N_EDGES + slot] = s;
  }
}

__global__ __launch_bounds__(256) void k_phi_mfma(
    const float* __restrict__ X, const float* __restrict__ W0,
    const float* __restrict__ b0, const float* __restrict__ W1,
    const float* __restrict__ b1, const float* __restrict__ dinv,
    const int* __restrict__ flag, float* __restrict__ P0,
    float* __restrict__ P1) {
  __shared__ ushort Ah[128 * 32], Al[128 * 32], Bh[128 * 32], Bl[128 * 32];
  const int tid = threadIdx.x;
  const int m0 = blockIdx.x * 128;
  const float* W = blockIdx.y ? W1 : W0;
  const float* bias = blockIdx.y ? b1 : b0;
  float* P = blockIdx.y ? P1 : P0;
  const int wid = tid >> 6, lane = tid & 63;
  const int wr = wid >> 1, wc = wid & 1;
  const int lr = lane & 15, k8 = lane >> 4;
  const int rt = tid >> 1, kb = (tid & 1) * 16;
  const bool mok = (m0 + rt) < N_NODES;
  const float* Xrow = X + (size_t)(m0 + rt) * F_IN;
  const float* Wrow = W + (size_t)rt * F_IN;
  f32x4 acc[4][4] = {};
  for (int k0 = 0; k0 < F_IN; k0 += 32) {
    float4 xa[4], wb[4];
#pragma unroll
    for (int j = 0; j < 4; ++j) {
      xa[j] = mok ? *(const float4*)(Xrow + k0 + kb + 4 * j)
                  : make_float4(0.f, 0.f, 0.f, 0.f);
      wb[j] = *(const float4*)(Wrow + k0 + kb + 4 * j);
    }
    if (k0) __syncthreads();
#pragma unroll
    for (int j = 0; j < 4; ++j) {
      int idx = rt * 32 + kb + 4 * j;
      ushort h0 = f2bf(xa[j].x), h1 = f2bf(xa[j].y), h2 = f2bf(xa[j].z), h3 = f2bf(xa[j].w);
      *(ushort4*)&Ah[idx] = make_ushort4(h0, h1, h2, h3);
      *(ushort4*)&Al[idx] =
          make_ushort4(f2bf(xa[j].x - bf2f(h0)), f2bf(xa[j].y - bf2f(h1)),
                       f2bf(xa[j].z - bf2f(h2)), f2bf(xa[j].w - bf2f(h3)));
      ushort g0 = f2bf(wb[j].x), g1 = f2bf(wb[j].y), g2 = f2bf(wb[j].z), g3 = f2bf(wb[j].w);
      *(ushort4*)&Bh[idx] = make_ushort4(g0, g1, g2, g3);
      *(ushort4*)&Bl[idx] =
          make_ushort4(f2bf(wb[j].x - bf2f(g0)), f2bf(wb[j].y - bf2f(g1)),
                       f2bf(wb[j].z - bf2f(g2)), f2bf(wb[j].w - bf2f(g3)));
    }
    __syncthreads();
    bf16x8 ah[4], al[4], bh[4], bl[4];
#pragma unroll
    for (int i = 0; i < 4; ++i) {
      int ao = (wr * 64 + i * 16 + lr) * 32 + k8 * 8;
      int bo = (wc * 64 + i * 16 + lr) * 32 + k8 * 8;
      ah[i] = *(const bf16x8*)&Ah[ao];
      al[i] = *(const bf16x8*)&Al[ao];
      bh[i] = *(const bf16x8*)&Bh[bo];
      bl[i] = *(const bf16x8*)&Bl[bo];
    }
#pragma unroll
    for (int i = 0; i < 4; ++i)
#pragma unroll
      for (int j = 0; j < 4; ++j) {
        acc[i][j] = __builtin_amdgcn_mfma_f32_16x16x32_bf16(ah[i], bh[j], acc[i][j], 0, 0, 0);
        acc[i][j] = __builtin_amdgcn_mfma_f32_16x16x32_bf16(ah[i], bl[j], acc[i][j], 0, 0, 0);
        acc[i][j] = __builtin_amdgcn_mfma_f32_16x16x32_bf16(al[i], bh[j], acc[i][j], 0, 0, 0);
      }
  }
  int iso = flag[1];
  float rsc[4][4];
#pragma unroll
  for (int i = 0; i < 4; ++i)
#pragma unroll
    for (int q = 0; q < 4; ++q) {
      int m = m0 + wr * 64 + i * 16 + k8 * 4 + q;
      rsc[i][q] = (m < N_NODES && !iso) ? dinv[m] : 1.0f;
    }
#pragma unroll
  for (int j = 0; j < 4; ++j) {
    int ch = wc * 64 + j * 16 + lr;
    float bv = bias[ch];
#pragma unroll
    for (int i = 0; i < 4; ++i) {
      int mbase = m0 + wr * 64 + i * 16 + k8 * 4;
#pragma unroll
      for (int q = 0; q < 4; ++q) {
        int m = mbase + q;
        if (m < N_NODES) P[(size_t)m * CH + ch] = (acc[i][j][q] + bv) * rsc[i][q];
      }
    }
  }
}

// Shared edge-accumulate body used by k_prop / k_gprop.
__device__ __forceinline__ void prop_accum(
    const float* __restrict__ xc, const void* __restrict__ csrv, int r, int iso,
    int e0, int e1, int g, int l, float4& acc0, float4& acc1) {
  if (!iso) {
    const int* csr = (const int*)csrv + (size_t)r * N_EDGES;
    for (int e = e0; e < e1; e += 16) {
      int lim = e1 - 1;
      int src[4]; float wgt[4];
#pragma unroll
      for (int u = 0; u < 4; ++u) {
        int ee = e + 4 * u + g;
        src[u] = csr[min(ee, lim)];
        wgt[u] = (ee <= lim) ? 1.f : 0.f;
      }
      float4 va[4], vb[4];
#pragma unroll
      for (int u = 0; u < 4; ++u) {
        const float4* rs = (const float4*)(xc + (size_t)src[u] * CH);
        va[u] = rs[l];
        vb[u] = rs[l + 16];
      }
#pragma unroll
      for (int u = 0; u < 4; ++u) {
        float w0 = wgt[u];
        acc0.x = fmaf(w0, va[u].x, acc0.x); acc0.y = fmaf(w0, va[u].y, acc0.y);
        acc0.z = fmaf(w0, va[u].z, acc0.z); acc0.w = fmaf(w0, va[u].w, acc0.w);
        acc1.x = fmaf(w0, vb[u].x, acc1.x); acc1.y = fmaf(w0, vb[u].y, acc1.y);
        acc1.z = fmaf(w0, vb[u].z, acc1.z); acc1.w = fmaf(w0, vb[u].w, acc1.w);
      }
    }
  } else {
    const int2* csr = (const int2*)csrv + (size_t)r * N_EDGES;
    for (int e = e0; e < e1; e += 16) {
      int lim = e1 - 1;
      int2 pm[4]; float wgt[4];
#pragma unroll
      for (int u = 0; u < 4; ++u) {
        int ee = e + 4 * u + g;
        pm[u] = csr[min(ee, lim)];
        wgt[u] = (ee <= lim) ? __int_as_float(pm[u].y) : 0.f;
      }
      float4 va[4], vb[4];
#pragma unroll
      for (int u = 0; u < 4; ++u) {
        const float4* rs = (const float4*)(xc + (size_t)pm[u].x * CH);
        va[u] = rs[l];
        vb[u] = rs[l + 16];
      }
#pragma unroll
      for (int u = 0; u < 4; ++u) {
        float w0 = wgt[u];
        acc0.x = fmaf(w0, va[u].x, acc0.x); acc0.y = fmaf(w0, va[u].y, acc0.y);
        acc0.z = fmaf(w0, va[u].z, acc0.z); acc0.w = fmaf(w0, va[u].w, acc0.w);
        acc1.x = fmaf(w0, vb[u].x, acc1.x); acc1.y = fmaf(w0, vb[u].y, acc1.y);
        acc1.z = fmaf(w0, vb[u].z, acc1.z); acc1.w = fmaf(w0, vb[u].w, acc1.w);
      }
    }
  }
}

// Fused-over-relations prop: grid.y indexes relation (rel = rel0 + blockIdx.y),
// state pointers advance by `slab` elements per y (slab=0 in fallback mode).
// out may alias `other` elementwise (read-before-write same thread), never xc.
__global__ __launch_bounds__(256, 6) void k_prop(
    const float* __restrict__ xcb, const float* __restrict__ otherb,
    float* __restrict__ outb, const int* __restrict__ off3,
    const void* __restrict__ csrv, const int* __restrict__ flag, int rel0,
    size_t slab, float wscale, float aself, float beta) {
  int node = blockIdx.x * 4 + (threadIdx.x >> 6);
  if (node >= N_NODES) return;
  int rel = rel0 + blockIdx.y;
  const float* xc = xcb + (size_t)blockIdx.y * slab;
  const float* other = otherb + (size_t)blockIdx.y * slab;
  float* out = outb + (size_t)blockIdx.y * slab;
  const int* off = off3 + rel * (N_NODES + 1);
  int iso = flag[1];
  int lane = threadIdx.x & 63;
  int g = lane >> 4, l = lane & 15;
  int e0 = off[node], e1 = off[node + 1];
  size_t base = (size_t)node * CH;
  int go = (g & 1) * 64;
  float4 sv = *(const float4*)(xc + base + go + 4 * l);
  float4 ov = *(const float4*)(other + base + go + 4 * l);
  float4 acc0 = make_float4(0.f, 0.f, 0.f, 0.f);
  float4 acc1 = make_float4(0.f, 0.f, 0.f, 0.f);
  prop_accum(xc, csrv, rel, iso, e0, e1, g, l, acc0, acc1);
#pragma unroll
  for (int m = 16; m < 64; m <<= 1) {
    acc0.x += __shfl_xor(acc0.x, m); acc0.y += __shfl_xor(acc0.y, m);
    acc0.z += __shfl_xor(acc0.z, m); acc0.w += __shfl_xor(acc0.w, m);
    acc1.x += __shfl_xor(acc1.x, m); acc1.y += __shfl_xor(acc1.y, m);
    acc1.z += __shfl_xor(acc1.z, m); acc1.w += __shfl_xor(acc1.w, m);
  }
  float ws2 = iso ? wscale : ((e1 > e0) ? wscale / (float)(e1 - e0) : 0.f);
  if (g == 0) {
    float4 o;
    o.x = ws2 * acc0.x + aself * sv.x + beta * ov.x;
    o.y = ws2 * acc0.y + aself * sv.y + beta * ov.y;
    o.z = ws2 * acc0.z + aself * sv.z + beta * ov.z;
    o.w = ws2 * acc0.w + aself * sv.w + beta * ov.w;
    *(float4*)(out + base + 4 * l) = o;
  } else if (g == 1) {
    float4 o;
    o.x = ws2 * acc1.x + aself * sv.x + beta * ov.x;
    o.y = ws2 * acc1.y + aself * sv.y + beta * ov.y;
    o.z = ws2 * acc1.z + aself * sv.z + beta * ov.z;
    o.w = ws2 * acc1.w + aself * sv.w + beta * ov.w;
    *(float4*)(out + base + 64 + 4 * l) = o;
  }
}

// Fused final step + batch gather (+ sqrt(deg) rescale on fast path).
__global__ __launch_bounds__(256) void k_gprop(
    const float* __restrict__ y3b, const float* __restrict__ y2b,
    const int* __restrict__ off3, const void* __restrict__ csrv,
    const int* __restrict__ flag, const int* __restrict__ batch,
    float* __restrict__ out, int rel0, size_t slab,
    float wscale, float aself, float beta) {
  int b = blockIdx.x * 4 + (threadIdx.x >> 6);
  if (b >= BATCH) return;
  int rel = rel0 + blockIdx.y;
  const float* y3 = y3b + (size_t)blockIdx.y * slab;
  const float* y2 = y2b + (size_t)blockIdx.y * slab;
  const int* off = off3 + rel * (N_NODES + 1);
  int i64 = flag[0], iso = flag[1];
  int node = i64 ? batch[2 * b] : batch[b];
  int lane = threadIdx.x & 63;
  int g = lane >> 4, l = lane & 15;
  int e0 = off[node], e1 = off[node + 1];
  size_t base = (size_t)node * CH;
  int go = (g & 1) * 64;
  float4 sv = *(const float4*)(y3 + base + go + 4 * l);
  float4 ov = *(const float4*)(y2 + base + go + 4 * l);
  float4 acc0 = make_float4(0.f, 0.f, 0.f, 0.f);
  float4 acc1 = make_float4(0.f, 0.f, 0.f, 0.f);
  prop_accum(y3, csrv, rel, iso, e0, e1, g, l, acc0, acc1);
#pragma unroll
  for (int m = 16; m < 64; m <<= 1) {
    acc0.x += __shfl_xor(acc0.x, m); acc0.y += __shfl_xor(acc0.y, m);
    acc0.z += __shfl_xor(acc0.z, m); acc0.w += __shfl_xor(acc0.w, m);
    acc1.x += __shfl_xor(acc1.x, m); acc1.y += __shfl_xor(acc1.y, m);
    acc1.z += __shfl_xor(acc1.z, m); acc1.w += __shfl_xor(acc1.w, m);
  }
  int deg = e1 - e0;
  float ws2 = iso ? wscale : ((deg > 0) ? wscale / (float)deg : 0.f);
  float osc = iso ? 1.0f : sqrtf((float)deg);
  float* orow = out + (size_t)b * (N_REL * CH) + rel * CH;
  if (g == 0) {
    float4 o;
    o.x = osc * (ws2 * acc0.x + aself * sv.x + beta * ov.x);
    o.y = osc * (ws2 * acc0.y + aself * sv.y + beta * ov.y);
    o.z = osc * (ws2 * acc0.z + aself * sv.z + beta * ov.z);
    o.w = osc * (ws2 * acc0.w + aself * sv.w + beta * ov.w);
    *(float4*)(orow + 4 * l) = o;
  } else if (g == 1) {
    float4 o;
    o.x = osc * (ws2 * acc1.x + aself * sv.x + beta * ov.x);
    o.y = osc * (ws2 * acc1.y + aself * sv.y + beta * ov.y);
    o.z = osc * (ws2 * acc1.z + aself * sv.z + beta * ov.z);
    o.w = osc * (ws2 * acc1.w + aself * sv.w + beta * ov.w);
    *(float4*)(orow + 64 + 4 * l) = o;
  }
}

extern "C" void kernel_launch(void* const* d_in, const int* in_sizes, int n_in,
                              void* d_out, int out_size, void* d_ws, size_t ws_size,
                              hipStream_t stream) {
  const float* features   = (const float*)d_in[0];
  const int*   edge_index = (const int*)d_in[1];
  const int*   batch_nodes= (const int*)d_in[2];
  const float* lin0_w     = (const float*)d_in[3];
  const float* lin0_b     = (const float*)d_in[4];
  const float* lin1_w     = (const float*)d_in[5];
  const float* lin1_b     = (const float*)d_in[6];
  float* out = (float*)d_out;

  const size_t slabElems = (size_t)N_NODES * CH;   // per-relation state elements
  // fixed part: flag + deg3 + cur3 + dinv3 + off3 + csr
  const size_t fixedBytes = 256 + 4 * (((size_t)3 * N_NODES * 4 + 255) & ~(size_t)255)
                            + (((size_t)3 * N_EDGES * 8 + 255) & ~(size_t)255) + 4096;
  const size_t fusedNeed = fixedBytes + 2 * 3 * slabElems * 4;
  const bool fused = ws_size >= fusedNeed;
  const size_t slab = fused ? slabElems : 0;   // pointer stride per grid.y
  const int nslab = fused ? 3 : 1;

  char* w = (char*)d_ws;
  size_t o = 0;
  auto nxt = [&](size_t bytes) {
    char* p = w + o;
    o = (o + bytes + 255) & ~(size_t)255;
    return p;
  };
  int*   flag  = (int*)  nxt(256);
  int*   deg3  = (int*)  nxt((size_t)3 * N_NODES * 4);
  int*   cur3  = (int*)  nxt((size_t)3 * N_NODES * 4);
  float* dinv3 = (float*)nxt((size_t)3 * N_NODES * 4);
  int*   off3  = (int*)  nxt((size_t)3 * (N_NODES + 1) * 4);
  void*  csr   = (void*) nxt((size_t)3 * N_EDGES * 8);
  float* A     = (float*)nxt((size_t)nslab * slabElems * 4);
  float* B     = (float*)nxt((size_t)nslab * slabElems * 4);

  hipMemsetAsync(flag, 0, 8, stream);
  hipMemsetAsync(deg3, 0, (size_t)3 * N_NODES * 4, stream);
  hipMemsetAsync(cur3, 0, (size_t)3 * N_NODES * 4, stream);
  k_detect<<<1, 64, 0, stream>>>(edge_index, flag);
  const int NCHUNK = (N_EDGES + 255) / 256;   // 3125
  k_hist3x<<<dim3(NCHUNK * NRANGE, 3), 256, 0, stream>>>(edge_index, flag, deg3);
  k_dinv3<<<(3 * N_NODES + 255) / 256, 256, 0, stream>>>(deg3, dinv3, flag);
  k_scan3<<<3, 1024, 0, stream>>>(deg3, off3);
  k_fill3x<<<dim3(NCHUNK * NRANGE, 3), 256, 0, stream>>>(edge_index, flag, off3,
                                                         cur3, dinv3, csr);

  const float h2 = DT * DT;
  // phi GEMMs (per relation; write q0 -> A slab, q1 -> B slab)
  for (int r = 0; r < N_REL; ++r) {
    float* Ar = A + (size_t)(fused ? r : 0) * slabElems;
    float* Br = B + (size_t)(fused ? r : 0) * slabElems;
    if (!fused && r > 0) break;   // fallback launches phi inside the r-loop below
    k_phi_mfma<<<dim3((N_NODES + 127) / 128, 2), 256, 0, stream>>>(
        features, lin0_w + (size_t)r * CH * F_IN, lin0_b + (size_t)r * CH,
        lin1_w + (size_t)r * CH * F_IN, lin1_b + (size_t)r * CH,
        dinv3 + r * N_NODES, flag, Ar, Br);
  }

  if (fused) {
    // A=q0, B=q1 per slab.
    // Y1 = dt*q1 + 0.5h^2*Sum(A) + A      -> B
    k_prop<<<dim3((N_NODES + 3) / 4, 3), 256, 0, stream>>>(
        A, B, B, off3, csr, flag, 0, slab, 0.5f * h2, 1.0f, DT);
    // Y2 = h^2*Sum(Y1) + 2*Y1 - q0        -> A
    k_prop<<<dim3((N_NODES + 3) / 4, 3), 256, 0, stream>>>(
        B, A, A, off3, csr, flag, 0, slab, h2, 2.0f, -1.0f);
    // Y3 = h^2*Sum(Y2) + 2*Y2 - Y1        -> B
    k_prop<<<dim3((N_NODES + 3) / 4, 3), 256, 0, stream>>>(
        A, B, B, off3, csr, flag, 0, slab, h2, 2.0f, -1.0f);
    // Y4[batch] fused with gather         -> out
    k_gprop<<<dim3((BATCH + 3) / 4, 3), 256, 0, stream>>>(
        B, A, off3, csr, flag, batch_nodes, out, 0, slab, h2, 2.0f, -1.0f);
  } else {
    for (int r = 0; r < N_REL; ++r) {
      if (r > 0) {   // phi for r==0 already launched above
        k_phi_mfma<<<dim3((N_NODES + 127) / 128, 2), 256, 0, stream>>>(
            features, lin0_w + (size_t)r * CH * F_IN, lin0_b + (size_t)r * CH,
            lin1_w + (size_t)r * CH * F_IN, lin1_b + (size_t)r * CH,
            dinv3 + r * N_NODES, flag, A, B);
      }
      k_prop<<<dim3((N_NODES + 3) / 4, 1), 256, 0, stream>>>(
          A, B, B, off3, csr, flag, r, 0, 0.5f * h2, 1.0f, DT);
      k_prop<<<dim3((N_NODES + 3) / 4, 1), 256, 0, stream>>>(
          B, A, A, off3, csr, flag, r, 0, h2, 2.0f, -1.0f);
      k_prop<<<dim3((N_NODES + 3) / 4, 1), 256, 0, stream>>>(
          A, B, B, off3, csr, flag, r, 0, h2, 2.0f, -1.0f);
      k_gprop<<<dim3((BATCH + 3) / 4, 1), 256, 0, stream>>>(
          B, A, off3, csr, flag, batch_nodes, out, r, 0, h2, 2.0f, -1.0f);
    }
  }
}